// Round 5
// baseline (1014.166 us; speedup 1.0000x reference)
//
#include <hip/hip_runtime.h>

// Problem constants
#define B_   4
#define NQ_  2048
#define NKV_ 2048
#define H_   16
#define DK_  64
#define DM_  1024
#define DKV_ 2048   // stacked K|V projection width

typedef _Float16 f16x8 __attribute__((ext_vector_type(8)));
typedef _Float16 f16x4 __attribute__((ext_vector_type(4)));
typedef float    f32x4 __attribute__((ext_vector_type(4)));

__device__ __forceinline__ void gload_lds16(const void* g, void* l) {
  __builtin_amdgcn_global_load_lds(
      (const __attribute__((address_space(1))) unsigned int*)g,
      (__attribute__((address_space(3))) unsigned int*)l, 16, 0, 0);
}

// ---------------- cast f32 -> f16 (4 elems/thread) ----------------
__global__ __launch_bounds__(256) void cast_f16(const float* __restrict__ in,
                                                _Float16* __restrict__ out, int n4) {
  int i = blockIdx.x * 256 + threadIdx.x;
  if (i >= n4) return;
  float4 v = ((const float4*)in)[i];
  f16x4 o = {(_Float16)v.x, (_Float16)v.y, (_Float16)v.z, (_Float16)v.w};
  *(f16x4*)(out + (size_t)i * 4) = o;
}

// ---------------- W [K][N] f32 -> Wt [N][K] f16 ----------------
__global__ __launch_bounds__(256) void wtrans(const float* __restrict__ W,
                                              _Float16* __restrict__ Wt) {
  __shared__ float tile[32][33];
  int bx = blockIdx.x & 31, by = blockIdx.x >> 5;
  int tx = threadIdx.x & 31, ty = threadIdx.x >> 5;  // ty 0..7
#pragma unroll
  for (int j = 0; j < 4; ++j)
    tile[ty + j * 8][tx] = W[(size_t)(by * 32 + ty + j * 8) * 1024 + bx * 32 + tx];
  __syncthreads();
#pragma unroll
  for (int j = 0; j < 4; ++j)
    Wt[(size_t)(bx * 32 + ty + j * 8) * 1024 + by * 32 + tx] = (_Float16)tile[tx][ty + j * 8];
}

// ---------------- GEMM: C[M][N] = A[M][K] @ Bt[N][K]^T (m97 structure) ----------------
template <int F32OUT>
__global__ __launch_bounds__(256, 2) void gemm_bt(const _Float16* __restrict__ A,
                                                  const _Float16* __restrict__ Bt,
                                                  void* __restrict__ Cp,
                                                  int M, int N, int K) {
  __shared__ _Float16 As[128 * 32];
  __shared__ _Float16 Bs[128 * 32];
  const int nbn = N >> 7;
  const int bm = blockIdx.x / nbn, bn = blockIdx.x % nbn;
  const int t = threadIdx.x, w = t >> 6, l = t & 63;
  const int lr = l & 15, lg = l >> 4;
  const int wr = w >> 1, wc = w & 1;
  const int m0 = bm << 7, n0 = bn << 7;

  f32x4 acc[4][4] = {};

  for (int k0 = 0; k0 < K; k0 += 32) {
#pragma unroll
    for (int p = 0; p < 2; ++p) {
      int off = p * 4096 + w * 1024 + l * 16;  // linear byte offset in 8KB tile
      int row = off >> 6;                       // 64B per row (32 f16)
      int col = (off & 63) >> 1;                // element col
      gload_lds16(A  + (size_t)(m0 + row) * K + k0 + col, (char*)As + p * 4096 + w * 1024);
      gload_lds16(Bt + (size_t)(n0 + row) * K + k0 + col, (char*)Bs + p * 4096 + w * 1024);
    }
    __syncthreads();
    f16x8 af[4], bq[4];
#pragma unroll
    for (int i = 0; i < 4; ++i) {
      af[i] = *(const f16x8*)((const char*)As + (wr * 64 + i * 16 + lr) * 64 + lg * 16);
      bq[i] = *(const f16x8*)((const char*)Bs + (wc * 64 + i * 16 + lr) * 64 + lg * 16);
    }
#pragma unroll
    for (int i = 0; i < 4; ++i)
#pragma unroll
      for (int j = 0; j < 4; ++j)
        acc[i][j] = __builtin_amdgcn_mfma_f32_16x16x32_f16(af[i], bq[j], acc[i][j], 0, 0, 0);
    __syncthreads();
  }
#pragma unroll
  for (int i = 0; i < 4; ++i)
#pragma unroll
    for (int j = 0; j < 4; ++j)
#pragma unroll
      for (int r = 0; r < 4; ++r) {
        size_t row = m0 + wr * 64 + i * 16 + lg * 4 + r;
        size_t col = n0 + wc * 64 + j * 16 + lr;
        if (F32OUT) ((float*)Cp)[row * N + col] = acc[i][j][r];
        else ((_Float16*)Cp)[row * N + col] = (_Float16)acc[i][j][r];
      }
}

// ---------------- V [b][kv][1024+h*64+d] -> Vt [b][h][d][kv] ----------------
__global__ __launch_bounds__(256) void vtrans(const _Float16* __restrict__ KVb,
                                              _Float16* __restrict__ Vt) {
  __shared__ _Float16 tile[64][72];  // [kv][d], padded rows (144B, 16B-aligned)
  int idx = blockIdx.x;
  int kt = idx & 31, h = (idx >> 5) & 15, b = idx >> 9;
  int kv0 = kt << 6;
  int t = threadIdx.x;
#pragma unroll
  for (int p = 0; p < 2; ++p) {
    int c = t + p * 256;
    int row = c >> 3, cb = (c & 7) * 16;
    f16x8 v = *(const f16x8*)(KVb + (size_t)(b * NKV_ + kv0 + row) * DKV_ + 1024 + h * 64 + cb / 2);
    *(f16x8*)((char*)&tile[row][0] + cb) = v;
  }
  __syncthreads();
  int d = t & 63, j0 = (t >> 6) * 2;
#pragma unroll
  for (int jj = 0; jj < 2; ++jj) {
    int kvs = (j0 + jj) * 8;
    f16x8 o;
#pragma unroll
    for (int u = 0; u < 8; ++u) o[u] = tile[kvs + u][d];
    *(f16x8*)(Vt + ((size_t)((b * H_ + h) * 64 + d)) * NKV_ + kv0 + kvs) = o;
  }
}

// ---------------- fused attention: softmax(Q K^T + bias) V ----------------
// BARRIER-FREE: K and V fragments read directly from global (L2/L3-resident);
// only per-wave P tile goes through LDS (wave-private, lgkmcnt ordering only).
// Each wave owns 32 q-rows (2 MFMA row-tiles) -> every K/V fragment feeds 4 MFMAs.
__global__ __launch_bounds__(256, 4) void attn(const _Float16* __restrict__ Qb,
                                               const _Float16* __restrict__ KVb,
                                               const _Float16* __restrict__ Vt,
                                               const float* __restrict__ bias,
                                               _Float16* __restrict__ ctx) {
  __shared__ _Float16 Ps[4][32 * 64];   // per-wave P tile (32 q-rows), swizzled
  int idx = blockIdx.x;
  int b = idx & 3, qt = (idx >> 2) & 15, h = idx >> 6;  // b innermost: bias strips shared by 4 consecutive blocks
  int t = threadIdx.x, w = t >> 6, l = t & 63, lr = l & 15, lg = l >> 4;
  int qw = (qt << 7) + (w << 5);  // this wave's 32 q-rows

  f16x8 aq[2][2];
#pragma unroll
  for (int qe = 0; qe < 2; ++qe) {
    const _Float16* qp = Qb + (size_t)(b * NQ_ + qw + qe * 16 + lr) * DM_ + h * 64 + lg * 8;
    aq[qe][0] = *(const f16x8*)qp;
    aq[qe][1] = *(const f16x8*)(qp + 32);
  }

  f32x4 acc[2][4] = {};
  float mrow[2][4], lsum[2][4];
#pragma unroll
  for (int qe = 0; qe < 2; ++qe)
#pragma unroll
    for (int r = 0; r < 4; ++r) { mrow[qe][r] = -1e30f; lsum[qe][r] = 0.f; }

  const _Float16* Kbase = KVb + (size_t)b * NKV_ * DKV_ + h * 64;
  const _Float16* Vtb   = Vt + (size_t)(b * H_ + h) * 64 * NKV_;
  const float*    biasb = bias + ((size_t)h * NQ_ + qw + lg * 4) * NKV_;

  for (int it = 0; it < 32; ++it) {
    const int kv0 = it << 6;

    // ---- bias loads issue first (latency hides under QK^T) ----
    float bv[2][4][4];
#pragma unroll
    for (int qe = 0; qe < 2; ++qe)
#pragma unroll
      for (int r = 0; r < 4; ++r) {
        const float* bp = biasb + (size_t)(qe * 16 + r) * NKV_ + kv0 + lr;
#pragma unroll
        for (int nt = 0; nt < 4; ++nt) bv[qe][nt][r] = bp[nt * 16];
      }

    // ---- S = Q K^T, K fragments straight from global ----
    f32x4 s[2][4];
#pragma unroll
    for (int nt = 0; nt < 4; ++nt) {
      const _Float16* kp = Kbase + (size_t)(kv0 + nt * 16 + lr) * DKV_ + lg * 8;
      f16x8 kf0 = *(const f16x8*)kp;
      f16x8 kf1 = *(const f16x8*)(kp + 32);
#pragma unroll
      for (int qe = 0; qe < 2; ++qe) {
        f32x4 z = {0.f, 0.f, 0.f, 0.f};
        z = __builtin_amdgcn_mfma_f32_16x16x32_f16(aq[qe][0], kf0, z, 0, 0, 0);
        s[qe][nt] = __builtin_amdgcn_mfma_f32_16x16x32_f16(aq[qe][1], kf1, z, 0, 0, 0);
      }
    }
#pragma unroll
    for (int qe = 0; qe < 2; ++qe)
#pragma unroll
      for (int nt = 0; nt < 4; ++nt)
#pragma unroll
        for (int r = 0; r < 4; ++r) s[qe][nt][r] += bv[qe][nt][r];

    // ---- online softmax (rows spread over 16-lane groups) ----
#pragma unroll
    for (int qe = 0; qe < 2; ++qe)
#pragma unroll
      for (int r = 0; r < 4; ++r) {
        float v = fmaxf(fmaxf(s[qe][0][r], s[qe][1][r]), fmaxf(s[qe][2][r], s[qe][3][r]));
        v = fmaxf(v, __shfl_xor(v, 1));
        v = fmaxf(v, __shfl_xor(v, 2));
        v = fmaxf(v, __shfl_xor(v, 4));
        v = fmaxf(v, __shfl_xor(v, 8));
        float mn = fmaxf(mrow[qe][r], v);
        float corr = __expf(mrow[qe][r] - mn);
        mrow[qe][r] = mn;
        float rs = 0.f;
#pragma unroll
        for (int nt = 0; nt < 4; ++nt) {
          float p = __expf(s[qe][nt][r] - mn);
          s[qe][nt][r] = p;
          rs += p;
        }
        rs += __shfl_xor(rs, 1);
        rs += __shfl_xor(rs, 2);
        rs += __shfl_xor(rs, 4);
        rs += __shfl_xor(rs, 8);
        lsum[qe][r] = lsum[qe][r] * corr + rs;
#pragma unroll
        for (int nt = 0; nt < 4; ++nt) acc[qe][nt][r] *= corr;
      }

    // ---- P (C-layout) -> per-wave LDS -> A-fragment layout (no barrier: wave-private) ----
#pragma unroll
    for (int qe = 0; qe < 2; ++qe)
#pragma unroll
      for (int r = 0; r < 4; ++r) {
        int row = qe * 16 + lg * 4 + r;
        int sw = (row & 7) << 4;
#pragma unroll
        for (int nt = 0; nt < 4; ++nt)
          *(_Float16*)((char*)Ps[w] + ((row * 128 + (nt * 16 + lr) * 2) ^ sw)) =
              (_Float16)s[qe][nt][r];
      }

    // ---- PV, V fragments straight from global Vt ----
#pragma unroll
    for (int kk = 0; kk < 2; ++kk) {
      f16x8 pa[2];
#pragma unroll
      for (int qe = 0; qe < 2; ++qe) {
        int prow = qe * 16 + lr;
        pa[qe] = *(const f16x8*)((char*)Ps[w] +
                 ((prow * 128 + kk * 64 + lg * 16) ^ ((prow & 7) << 4)));
      }
#pragma unroll
      for (int nt = 0; nt < 4; ++nt) {
        const _Float16* vp = Vtb + (size_t)(nt * 16 + lr) * NKV_ + kv0 + kk * 32 + lg * 8;
        f16x8 vf = *(const f16x8*)vp;
#pragma unroll
        for (int qe = 0; qe < 2; ++qe)
          acc[qe][nt] = __builtin_amdgcn_mfma_f32_16x16x32_f16(pa[qe], vf, acc[qe][nt], 0, 0, 0);
      }
    }
  }

  // ---- normalize + write ctx[b][q][h*64+d] f16 ----
#pragma unroll
  for (int qe = 0; qe < 2; ++qe)
#pragma unroll
    for (int nt = 0; nt < 4; ++nt)
#pragma unroll
      for (int r = 0; r < 4; ++r) {
        float o = acc[qe][nt][r] / lsum[qe][r];
        size_t q = qw + qe * 16 + lg * 4 + r;
        ctx[((size_t)b * NQ_ + q) * DM_ + h * 64 + nt * 16 + lr] = (_Float16)o;
      }
}

extern "C" void kernel_launch(void* const* d_in, const int* in_sizes, int n_in,
                              void* d_out, int out_size, void* d_ws, size_t ws_size,
                              hipStream_t stream) {
  const float* x    = (const float*)d_in[0];
  const float* enc  = (const float*)d_in[1];
  const float* bias = (const float*)d_in[2];
  const float* Wq   = (const float*)d_in[3];
  const float* Wk   = (const float*)d_in[4];
  const float* Wv   = (const float*)d_in[5];
  const float* Wo   = (const float*)d_in[6];
  char* ws = (char*)d_ws;
  const size_t MiB = 1024 * 1024;
  _Float16* WqT   = (_Float16*)(ws + 0 * MiB);
  _Float16* WkT   = (_Float16*)(ws + 2 * MiB);   // WkT+WvT contiguous: stacked Bt [2048][1024]
  _Float16* WvT   = (_Float16*)(ws + 4 * MiB);
  _Float16* WoT   = (_Float16*)(ws + 6 * MiB);
  _Float16* xf    = (_Float16*)(ws + 8 * MiB);
  _Float16* encf  = (_Float16*)(ws + 24 * MiB);
  _Float16* Qb    = (_Float16*)(ws + 40 * MiB);
  _Float16* KVb   = (_Float16*)(ws + 56 * MiB);  // [8192][2048]: cols 0..1023=K, 1024..2047=V
  _Float16* Vt    = (_Float16*)(ws + 88 * MiB);  // [B][H][64][NKV]
  _Float16* ctxf  = (_Float16*)(ws + 104 * MiB); // [8192][1024]

  wtrans<<<1024, 256, 0, stream>>>(Wq, WqT);
  wtrans<<<1024, 256, 0, stream>>>(Wk, WkT);
  wtrans<<<1024, 256, 0, stream>>>(Wv, WvT);
  wtrans<<<1024, 256, 0, stream>>>(Wo, WoT);
  cast_f16<<<8192, 256, 0, stream>>>(x, xf, 2097152);
  cast_f16<<<8192, 256, 0, stream>>>(enc, encf, 2097152);
  gemm_bt<0><<<512, 256, 0, stream>>>(xf, WqT, Qb, 8192, 1024, 1024);
  gemm_bt<0><<<1024, 256, 0, stream>>>(encf, WkT, KVb, 8192, 2048, 1024);
  vtrans<<<2048, 256, 0, stream>>>(KVb, Vt);
  attn<<<1024, 256, 0, stream>>>(Qb, KVb, Vt, bias, ctxf);
  gemm_bt<1><<<512, 256, 0, stream>>>(ctxf, WoT, d_out, 8192, 1024, 1024);
}

// Round 6
// 398.127 us; speedup vs baseline: 2.5473x; 2.5473x over previous
//
#include <hip/hip_runtime.h>

// Problem constants
#define B_   4
#define NQ_  2048
#define NKV_ 2048
#define H_   16
#define DK_  64
#define DM_  1024
#define DKV_ 2048   // stacked K|V projection width

typedef _Float16 f16x8 __attribute__((ext_vector_type(8)));
typedef _Float16 f16x4 __attribute__((ext_vector_type(4)));
typedef float    f32x4 __attribute__((ext_vector_type(4)));

__device__ __forceinline__ void gload_lds16(const void* g, void* l) {
  __builtin_amdgcn_global_load_lds(
      (const __attribute__((address_space(1))) unsigned int*)g,
      (__attribute__((address_space(3))) unsigned int*)l, 16, 0, 0);
}

// ---------------- cast f32 -> f16 (4 elems/thread) ----------------
__global__ __launch_bounds__(256) void cast_f16(const float* __restrict__ in,
                                                _Float16* __restrict__ out, int n4) {
  int i = blockIdx.x * 256 + threadIdx.x;
  if (i >= n4) return;
  float4 v = ((const float4*)in)[i];
  f16x4 o = {(_Float16)v.x, (_Float16)v.y, (_Float16)v.z, (_Float16)v.w};
  *(f16x4*)(out + (size_t)i * 4) = o;
}

// ---------------- W [K][N] f32 -> Wt [N][K] f16 ----------------
__global__ __launch_bounds__(256) void wtrans(const float* __restrict__ W,
                                              _Float16* __restrict__ Wt) {
  __shared__ float tile[32][33];
  int bx = blockIdx.x & 31, by = blockIdx.x >> 5;
  int tx = threadIdx.x & 31, ty = threadIdx.x >> 5;  // ty 0..7
#pragma unroll
  for (int j = 0; j < 4; ++j)
    tile[ty + j * 8][tx] = W[(size_t)(by * 32 + ty + j * 8) * 1024 + bx * 32 + tx];
  __syncthreads();
#pragma unroll
  for (int j = 0; j < 4; ++j)
    Wt[(size_t)(bx * 32 + ty + j * 8) * 1024 + by * 32 + tx] = (_Float16)tile[tx][ty + j * 8];
}

// ---------------- GEMM: C[M][N] = A[M][K] @ Bt[N][K]^T (m97 structure) ----------------
template <int F32OUT>
__global__ __launch_bounds__(256, 2) void gemm_bt(const _Float16* __restrict__ A,
                                                  const _Float16* __restrict__ Bt,
                                                  void* __restrict__ Cp,
                                                  int M, int N, int K) {
  __shared__ _Float16 As[128 * 32];
  __shared__ _Float16 Bs[128 * 32];
  const int nbn = N >> 7;
  const int bm = blockIdx.x / nbn, bn = blockIdx.x % nbn;
  const int t = threadIdx.x, w = t >> 6, l = t & 63;
  const int lr = l & 15, lg = l >> 4;
  const int wr = w >> 1, wc = w & 1;
  const int m0 = bm << 7, n0 = bn << 7;

  f32x4 acc[4][4] = {};

  for (int k0 = 0; k0 < K; k0 += 32) {
#pragma unroll
    for (int p = 0; p < 2; ++p) {
      int off = p * 4096 + w * 1024 + l * 16;  // linear byte offset in 8KB tile
      int row = off >> 6;                       // 64B per row (32 f16)
      int col = (off & 63) >> 1;                // element col
      gload_lds16(A  + (size_t)(m0 + row) * K + k0 + col, (char*)As + p * 4096 + w * 1024);
      gload_lds16(Bt + (size_t)(n0 + row) * K + k0 + col, (char*)Bs + p * 4096 + w * 1024);
    }
    __syncthreads();
    f16x8 af[4], bq[4];
#pragma unroll
    for (int i = 0; i < 4; ++i) {
      af[i] = *(const f16x8*)((const char*)As + (wr * 64 + i * 16 + lr) * 64 + lg * 16);
      bq[i] = *(const f16x8*)((const char*)Bs + (wc * 64 + i * 16 + lr) * 64 + lg * 16);
    }
#pragma unroll
    for (int i = 0; i < 4; ++i)
#pragma unroll
      for (int j = 0; j < 4; ++j)
        acc[i][j] = __builtin_amdgcn_mfma_f32_16x16x32_f16(af[i], bq[j], acc[i][j], 0, 0, 0);
    __syncthreads();
  }
#pragma unroll
  for (int i = 0; i < 4; ++i)
#pragma unroll
    for (int j = 0; j < 4; ++j)
#pragma unroll
      for (int r = 0; r < 4; ++r) {
        size_t row = m0 + wr * 64 + i * 16 + lg * 4 + r;
        size_t col = n0 + wc * 64 + j * 16 + lr;
        if (F32OUT) ((float*)Cp)[row * N + col] = acc[i][j][r];
        else ((_Float16*)Cp)[row * N + col] = (_Float16)acc[i][j][r];
      }
}

// ---------------- V [b][kv][1024+h*64+d] -> Vt [b][h][d][kv] ----------------
__global__ __launch_bounds__(256) void vtrans(const _Float16* __restrict__ KVb,
                                              _Float16* __restrict__ Vt) {
  __shared__ _Float16 tile[64][72];  // [kv][d], padded rows (144B, 16B-aligned)
  int idx = blockIdx.x;
  int kt = idx & 31, h = (idx >> 5) & 15, b = idx >> 9;
  int kv0 = kt << 6;
  int t = threadIdx.x;
#pragma unroll
  for (int p = 0; p < 2; ++p) {
    int c = t + p * 256;
    int row = c >> 3, cb = (c & 7) * 16;
    f16x8 v = *(const f16x8*)(KVb + (size_t)(b * NKV_ + kv0 + row) * DKV_ + 1024 + h * 64 + cb / 2);
    *(f16x8*)((char*)&tile[row][0] + cb) = v;
  }
  __syncthreads();
  int d = t & 63, j0 = (t >> 6) * 2;
#pragma unroll
  for (int jj = 0; jj < 2; ++jj) {
    int kvs = (j0 + jj) * 8;
    f16x8 o;
#pragma unroll
    for (int u = 0; u < 8; ++u) o[u] = tile[kvs + u][d];
    *(f16x8*)(Vt + ((size_t)((b * H_ + h) * 64 + d)) * NKV_ + kv0 + kvs) = o;
  }
}

// ---------------- fused attention: softmax(Q K^T + bias) V ----------------
// Round-3 structure (QBLK=64, 4 waves x 16 rows, single-buffer LDS, 2 barriers)
// + issue-early/write-late K/V staging + bias prefetch + setprio + exp2 softmax.
__global__ __launch_bounds__(256, 2) void attn(const _Float16* __restrict__ Qb,
                                               const _Float16* __restrict__ KVb,
                                               const _Float16* __restrict__ Vt,
                                               const float* __restrict__ bias,
                                               _Float16* __restrict__ ctx) {
  __shared__ _Float16 Ks[64 * 64];      // [kv][d], XOR-swizzled rows
  __shared__ _Float16 Vs[64 * 64];      // [d][kv], XOR-swizzled rows
  __shared__ _Float16 Ps[4][16 * 64];   // per-wave P tile, XOR-swizzled
  const float LOG2E = 1.44269504f;
  int idx = blockIdx.x;
  int b = idx & 3, qt = (idx >> 2) & 31, h = idx >> 7;  // batch innermost: bias L2/L3 reuse
  int t = threadIdx.x, w = t >> 6, l = t & 63, lr = l & 15, lg = l >> 4;
  int qw = (qt << 6) + (w << 4);

  const _Float16* qp = Qb + (size_t)(b * NQ_ + qw + lr) * DM_ + h * 64 + lg * 8;
  f16x8 aq0 = *(const f16x8*)qp;
  f16x8 aq1 = *(const f16x8*)(qp + 32);
  // pre-scale Q by log2(e): QK^T lands directly in exp2 domain
#pragma unroll
  for (int u = 0; u < 8; ++u) { aq0[u] = aq0[u] * (_Float16)LOG2E; aq1[u] = aq1[u] * (_Float16)LOG2E; }

  f32x4 acc[4] = {};
  float mrow[4] = {-1e30f, -1e30f, -1e30f, -1e30f};
  float lsum[4] = {0.f, 0.f, 0.f, 0.f};

  const _Float16* Kbase = KVb + (size_t)b * NKV_ * DKV_ + h * 64;
  const _Float16* Vtb   = Vt + (size_t)(b * H_ + h) * 64 * NKV_;
  const float*    biasb = bias + ((size_t)h * NQ_ + qw + lg * 4) * NKV_;

  const int srow = t >> 3;        // staging row (p adds 32)
  const int scb  = (t & 7) * 16;  // staging byte col within 128B row

  f16x8 kreg[2], vreg[2];
  float bv[4][4], bvn[4][4];

  auto LOADKV = [&](int kv0) {
#pragma unroll
    for (int p = 0; p < 2; ++p) {
      int row = srow + p * 32;
      kreg[p] = *(const f16x8*)(Kbase + (size_t)(kv0 + row) * DKV_ + scb / 2);
      vreg[p] = *(const f16x8*)(Vtb + (size_t)row * NKV_ + kv0 + scb / 2);
    }
  };
  auto LOADBIAS = [&](int kv0, float (&dst)[4][4]) {
#pragma unroll
    for (int r = 0; r < 4; ++r) {
      const float* bp = biasb + (size_t)r * NKV_ + kv0 + lr;
#pragma unroll
      for (int nt = 0; nt < 4; ++nt) dst[nt][r] = bp[nt * 16] * LOG2E;
    }
  };

  // prologue: tile0 -> regs
  LOADKV(0);
  LOADBIAS(0, bv);

  for (int it = 0; it < 32; ++it) {
    const int kv0 = it << 6;

    // ---- write staged regs (tile it) to LDS ----
#pragma unroll
    for (int p = 0; p < 2; ++p) {
      int row = srow + p * 32;
      int off = (row * 128 + scb) ^ ((row & 7) << 4);
      *(f16x8*)((char*)Ks + off) = kreg[p];
      *(f16x8*)((char*)Vs + off) = vreg[p];
    }
    __syncthreads();

    // ---- issue next tile's global loads (consumed next iteration) ----
    const int kvn = (it < 31) ? kv0 + 64 : kv0;
    LOADKV(kvn);

    // ---- S = Q K^T (exp2 domain) ----
    f32x4 s[4];
    __builtin_amdgcn_s_setprio(1);
#pragma unroll
    for (int nt = 0; nt < 4; ++nt) {
      int row = nt * 16 + lr;
      int sw = (row & 7) << 4;
      f16x8 kf0 = *(const f16x8*)((char*)Ks + ((row * 128 + lg * 16) ^ sw));
      f16x8 kf1 = *(const f16x8*)((char*)Ks + ((row * 128 + 64 + lg * 16) ^ sw));
      f32x4 z = {0.f, 0.f, 0.f, 0.f};
      z = __builtin_amdgcn_mfma_f32_16x16x32_f16(aq0, kf0, z, 0, 0, 0);
      s[nt] = __builtin_amdgcn_mfma_f32_16x16x32_f16(aq1, kf1, z, 0, 0, 0);
    }
    __builtin_amdgcn_s_setprio(0);

    // ---- + bias (prefetched), then prefetch next bias tile ----
#pragma unroll
    for (int nt = 0; nt < 4; ++nt)
#pragma unroll
      for (int r = 0; r < 4; ++r) s[nt][r] += bv[nt][r];
    LOADBIAS((it < 31) ? kv0 + 64 : kv0, bvn);

    // ---- online softmax (exp2 domain; rows spread over 16-lane groups) ----
#pragma unroll
    for (int r = 0; r < 4; ++r) {
      float v = fmaxf(fmaxf(s[0][r], s[1][r]), fmaxf(s[2][r], s[3][r]));
      v = fmaxf(v, __shfl_xor(v, 1));
      v = fmaxf(v, __shfl_xor(v, 2));
      v = fmaxf(v, __shfl_xor(v, 4));
      v = fmaxf(v, __shfl_xor(v, 8));
      float mn = fmaxf(mrow[r], v);
      float corr = exp2f(mrow[r] - mn);
      mrow[r] = mn;
      float rs = 0.f;
#pragma unroll
      for (int nt = 0; nt < 4; ++nt) {
        float p = exp2f(s[nt][r] - mn);
        s[nt][r] = p;
        rs += p;
      }
      rs += __shfl_xor(rs, 1);
      rs += __shfl_xor(rs, 2);
      rs += __shfl_xor(rs, 4);
      rs += __shfl_xor(rs, 8);
      lsum[r] = lsum[r] * corr + rs;
#pragma unroll
      for (int nt = 0; nt < 4; ++nt) acc[nt][r] *= corr;
    }

    // ---- P (C-layout) -> per-wave LDS -> A-fragment layout ----
#pragma unroll
    for (int r = 0; r < 4; ++r) {
      int row = lg * 4 + r;
      int sw = (row & 7) << 4;
#pragma unroll
      for (int nt = 0; nt < 4; ++nt)
        *(_Float16*)((char*)Ps[w] + ((row * 128 + (nt * 16 + lr) * 2) ^ sw)) =
            (_Float16)s[nt][r];
    }

    // ---- PV ----
    __builtin_amdgcn_s_setprio(1);
#pragma unroll
    for (int kk = 0; kk < 2; ++kk) {
      f16x8 pa = *(const f16x8*)((char*)Ps[w] +
                 ((lr * 128 + kk * 64 + lg * 16) ^ ((lr & 7) << 4)));
#pragma unroll
      for (int nt = 0; nt < 4; ++nt) {
        int row = nt * 16 + lr;
        f16x8 vf = *(const f16x8*)((char*)Vs +
                 ((row * 128 + kk * 64 + lg * 16) ^ ((row & 7) << 4)));
        acc[nt] = __builtin_amdgcn_mfma_f32_16x16x32_f16(pa, vf, acc[nt], 0, 0, 0);
      }
    }
    __builtin_amdgcn_s_setprio(0);
    __syncthreads();

    // rotate bias prefetch regs
#pragma unroll
    for (int nt = 0; nt < 4; ++nt)
#pragma unroll
      for (int r = 0; r < 4; ++r) bv[nt][r] = bvn[nt][r];
  }

  // ---- normalize + write ctx[b][q][h*64+d] f16 ----
#pragma unroll
  for (int r = 0; r < 4; ++r) {
    float inv = 1.0f / lsum[r];
#pragma unroll
    for (int nt = 0; nt < 4; ++nt) {
      float o = acc[nt][r] * inv;
      size_t q = qw + lg * 4 + r;
      ctx[((size_t)b * NQ_ + q) * DM_ + h * 64 + nt * 16 + lr] = (_Float16)o;
    }
  }
}

extern "C" void kernel_launch(void* const* d_in, const int* in_sizes, int n_in,
                              void* d_out, int out_size, void* d_ws, size_t ws_size,
                              hipStream_t stream) {
  const float* x    = (const float*)d_in[0];
  const float* enc  = (const float*)d_in[1];
  const float* bias = (const float*)d_in[2];
  const float* Wq   = (const float*)d_in[3];
  const float* Wk   = (const float*)d_in[4];
  const float* Wv   = (const float*)d_in[5];
  const float* Wo   = (const float*)d_in[6];
  char* ws = (char*)d_ws;
  const size_t MiB = 1024 * 1024;
  _Float16* WqT   = (_Float16*)(ws + 0 * MiB);
  _Float16* WkT   = (_Float16*)(ws + 2 * MiB);   // WkT+WvT contiguous: stacked Bt [2048][1024]
  _Float16* WvT   = (_Float16*)(ws + 4 * MiB);
  _Float16* WoT   = (_Float16*)(ws + 6 * MiB);
  _Float16* xf    = (_Float16*)(ws + 8 * MiB);
  _Float16* encf  = (_Float16*)(ws + 24 * MiB);
  _Float16* Qb    = (_Float16*)(ws + 40 * MiB);
  _Float16* KVb   = (_Float16*)(ws + 56 * MiB);  // [8192][2048]: cols 0..1023=K, 1024..2047=V
  _Float16* Vt    = (_Float16*)(ws + 88 * MiB);  // [B][H][64][NKV]
  _Float16* ctxf  = (_Float16*)(ws + 104 * MiB); // [8192][1024]

  wtrans<<<1024, 256, 0, stream>>>(Wq, WqT);
  wtrans<<<1024, 256, 0, stream>>>(Wk, WkT);
  wtrans<<<1024, 256, 0, stream>>>(Wv, WvT);
  wtrans<<<1024, 256, 0, stream>>>(Wo, WoT);
  cast_f16<<<8192, 256, 0, stream>>>(x, xf, 2097152);
  cast_f16<<<8192, 256, 0, stream>>>(enc, encf, 2097152);
  gemm_bt<0><<<512, 256, 0, stream>>>(xf, WqT, Qb, 8192, 1024, 1024);
  gemm_bt<0><<<1024, 256, 0, stream>>>(encf, WkT, KVb, 8192, 2048, 1024);
  vtrans<<<2048, 256, 0, stream>>>(KVb, Vt);
  attn<<<2048, 256, 0, stream>>>(Qb, KVb, Vt, bias, ctxf);
  gemm_bt<1><<<512, 256, 0, stream>>>(ctxf, WoT, d_out, 8192, 1024, 1024);
}

// Round 7
// 353.062 us; speedup vs baseline: 2.8725x; 1.1276x over previous
//
#include <hip/hip_runtime.h>

// Problem constants
#define B_   4
#define NQ_  2048
#define NKV_ 2048
#define H_   16
#define DK_  64
#define DM_  1024
#define DKV_ 2048   // stacked K|V projection width

typedef _Float16 f16x8 __attribute__((ext_vector_type(8)));
typedef _Float16 f16x4 __attribute__((ext_vector_type(4)));
typedef float    f32x4 __attribute__((ext_vector_type(4)));

__device__ __forceinline__ void gload_lds16(const void* g, void* l) {
  __builtin_amdgcn_global_load_lds(
      (const __attribute__((address_space(1))) unsigned int*)g,
      (__attribute__((address_space(3))) unsigned int*)l, 16, 0, 0);
}

// ---------------- cast f32 -> f16 (4 elems/thread) ----------------
__global__ __launch_bounds__(256) void cast_f16(const float* __restrict__ in,
                                                _Float16* __restrict__ out, int n4) {
  int i = blockIdx.x * 256 + threadIdx.x;
  if (i >= n4) return;
  float4 v = ((const float4*)in)[i];
  f16x4 o = {(_Float16)v.x, (_Float16)v.y, (_Float16)v.z, (_Float16)v.w};
  *(f16x4*)(out + (size_t)i * 4) = o;
}

// ---------------- W [K][N] f32 -> Wt [N][K] f16 ----------------
__global__ __launch_bounds__(256) void wtrans(const float* __restrict__ W,
                                              _Float16* __restrict__ Wt) {
  __shared__ float tile[32][33];
  int bx = blockIdx.x & 31, by = blockIdx.x >> 5;
  int tx = threadIdx.x & 31, ty = threadIdx.x >> 5;  // ty 0..7
#pragma unroll
  for (int j = 0; j < 4; ++j)
    tile[ty + j * 8][tx] = W[(size_t)(by * 32 + ty + j * 8) * 1024 + bx * 32 + tx];
  __syncthreads();
#pragma unroll
  for (int j = 0; j < 4; ++j)
    Wt[(size_t)(bx * 32 + ty + j * 8) * 1024 + by * 32 + tx] = (_Float16)tile[tx][ty + j * 8];
}

// ---------------- GEMM: C[M][N] = A[M][K] @ Bt[N][K]^T (m97 structure) ----------------
template <int F32OUT>
__global__ __launch_bounds__(256, 2) void gemm_bt(const _Float16* __restrict__ A,
                                                  const _Float16* __restrict__ Bt,
                                                  void* __restrict__ Cp,
                                                  int M, int N, int K) {
  __shared__ _Float16 As[128 * 32];
  __shared__ _Float16 Bs[128 * 32];
  const int nbn = N >> 7;
  const int bm = blockIdx.x / nbn, bn = blockIdx.x % nbn;
  const int t = threadIdx.x, w = t >> 6, l = t & 63;
  const int lr = l & 15, lg = l >> 4;
  const int wr = w >> 1, wc = w & 1;
  const int m0 = bm << 7, n0 = bn << 7;

  f32x4 acc[4][4] = {};

  for (int k0 = 0; k0 < K; k0 += 32) {
#pragma unroll
    for (int p = 0; p < 2; ++p) {
      int off = p * 4096 + w * 1024 + l * 16;  // linear byte offset in 8KB tile
      int row = off >> 6;                       // 64B per row (32 f16)
      int col = (off & 63) >> 1;                // element col
      gload_lds16(A  + (size_t)(m0 + row) * K + k0 + col, (char*)As + p * 4096 + w * 1024);
      gload_lds16(Bt + (size_t)(n0 + row) * K + k0 + col, (char*)Bs + p * 4096 + w * 1024);
    }
    __syncthreads();
    f16x8 af[4], bq[4];
#pragma unroll
    for (int i = 0; i < 4; ++i) {
      af[i] = *(const f16x8*)((const char*)As + (wr * 64 + i * 16 + lr) * 64 + lg * 16);
      bq[i] = *(const f16x8*)((const char*)Bs + (wc * 64 + i * 16 + lr) * 64 + lg * 16);
    }
#pragma unroll
    for (int i = 0; i < 4; ++i)
#pragma unroll
      for (int j = 0; j < 4; ++j)
        acc[i][j] = __builtin_amdgcn_mfma_f32_16x16x32_f16(af[i], bq[j], acc[i][j], 0, 0, 0);
    __syncthreads();
  }
#pragma unroll
  for (int i = 0; i < 4; ++i)
#pragma unroll
    for (int j = 0; j < 4; ++j)
#pragma unroll
      for (int r = 0; r < 4; ++r) {
        size_t row = m0 + wr * 64 + i * 16 + lg * 4 + r;
        size_t col = n0 + wc * 64 + j * 16 + lr;
        if (F32OUT) ((float*)Cp)[row * N + col] = acc[i][j][r];
        else ((_Float16*)Cp)[row * N + col] = (_Float16)acc[i][j][r];
      }
}

// ---------------- V [b][kv][1024+h*64+d] -> Vt [b][h][d][kv] ----------------
__global__ __launch_bounds__(256) void vtrans(const _Float16* __restrict__ KVb,
                                              _Float16* __restrict__ Vt) {
  __shared__ _Float16 tile[64][72];  // [kv][d], padded rows (144B, 16B-aligned)
  int idx = blockIdx.x;
  int kt = idx & 31, h = (idx >> 5) & 15, b = idx >> 9;
  int kv0 = kt << 6;
  int t = threadIdx.x;
#pragma unroll
  for (int p = 0; p < 2; ++p) {
    int c = t + p * 256;
    int row = c >> 3, cb = (c & 7) * 16;
    f16x8 v = *(const f16x8*)(KVb + (size_t)(b * NKV_ + kv0 + row) * DKV_ + 1024 + h * 64 + cb / 2);
    *(f16x8*)((char*)&tile[row][0] + cb) = v;
  }
  __syncthreads();
  int d = t & 63, j0 = (t >> 6) * 2;
#pragma unroll
  for (int jj = 0; jj < 2; ++jj) {
    int kvs = (j0 + jj) * 8;
    f16x8 o;
#pragma unroll
    for (int u = 0; u < 8; ++u) o[u] = tile[kvs + u][d];
    *(f16x8*)(Vt + ((size_t)((b * H_ + h) * 64 + d)) * NKV_ + kv0 + kvs) = o;
  }
}

// ---------------- fused attention: softmax(Q K^T + bias) V ----------------
// SWAPPED-OPERAND layout: S^T = mfma(K,Q) puts a full q-row's kv-slice in ONE
// lane (16 kv/lane) -> row reduce = 15 in-lane ops + 2 shuffles. PV swapped
// too (acc^T = mfma(V^T, P^T)). Defer-max (THR=8, exp2 domain). Single-buffer
// LDS, issue-early/write-late K/V staging, 2 barriers/tile.
__global__ __launch_bounds__(256, 4) void attn(const _Float16* __restrict__ Qb,
                                               const _Float16* __restrict__ KVb,
                                               const _Float16* __restrict__ Vt,
                                               const float* __restrict__ bias,
                                               _Float16* __restrict__ ctx) {
  __shared__ _Float16 Ks[64 * 64];      // [kv][d], XOR-swizzled rows
  __shared__ _Float16 Vs[64 * 64];      // [d][kv], XOR-swizzled rows
  __shared__ _Float16 Ps[4][16 * 64];   // per-wave P^T as [q][kv], XOR-swizzled
  const float LOG2E = 1.44269504f;
  int idx = blockIdx.x;
  int b = idx & 3, qt = (idx >> 2) & 31, h = idx >> 7;  // batch innermost: bias L2/L3 reuse
  int t = threadIdx.x, w = t >> 6, l = t & 63, lr = l & 15, lg = l >> 4;
  int qw = (qt << 6) + (w << 4);

  const _Float16* qp = Qb + (size_t)(b * NQ_ + qw + lr) * DM_ + h * 64 + lg * 8;
  f16x8 aq0 = *(const f16x8*)qp;
  f16x8 aq1 = *(const f16x8*)(qp + 32);
  // pre-scale Q by log2(e): QK^T lands directly in exp2 domain
#pragma unroll
  for (int u = 0; u < 8; ++u) { aq0[u] = aq0[u] * (_Float16)LOG2E; aq1[u] = aq1[u] * (_Float16)LOG2E; }

  f32x4 acc[4] = {};          // acc^T: [d-tile nt][r], d = nt*16+lg*4+r, q = lr
  float mrow = -1e30f;        // running max for q = qw+lr (exp2 domain)
  float lsum = 0.f;

  const _Float16* Kbase = KVb + (size_t)b * NKV_ * DKV_ + h * 64;
  const _Float16* Vtb   = Vt + (size_t)(b * H_ + h) * 64 * NKV_;
  const float*    biasq = bias + ((size_t)h * NQ_ + qw + lr) * NKV_ + lg * 4;  // per-lane q row

  const int srow = t >> 3;        // staging row (p adds 32)
  const int scb  = (t & 7) * 16;  // staging byte col within 128B row

  f16x8 kreg[2], vreg[2];

  auto LOADKV = [&](int kv0) {
#pragma unroll
    for (int p = 0; p < 2; ++p) {
      int row = srow + p * 32;
      kreg[p] = *(const f16x8*)(Kbase + (size_t)(kv0 + row) * DKV_ + scb / 2);
      vreg[p] = *(const f16x8*)(Vtb + (size_t)row * NKV_ + kv0 + scb / 2);
    }
  };

  // prologue: tile0 -> regs
  LOADKV(0);

  for (int it = 0; it < 32; ++it) {
    const int kv0 = it << 6;

    // ---- write staged regs (tile it) to LDS ----
#pragma unroll
    for (int p = 0; p < 2; ++p) {
      int row = srow + p * 32;
      int off = (row * 128 + scb) ^ ((row & 7) << 4);
      *(f16x8*)((char*)Ks + off) = kreg[p];
      *(f16x8*)((char*)Vs + off) = vreg[p];
    }
    __syncthreads();

    // ---- issue next tile's global loads (consumed next iteration) ----
    const int kvn = (it < 31) ? kv0 + 64 : kv0;
    LOADKV(kvn);

    // ---- bias loads (float4, contiguous kv per lane), cover under QK^T ----
    float4 bv4[4];
#pragma unroll
    for (int nt = 0; nt < 4; ++nt)
      bv4[nt] = *(const float4*)(biasq + kv0 + nt * 16);

    // ---- S^T = K Q^T: lane holds S[kv = nt*16+lg*4+r][q = lr] ----
    f32x4 s[4];
    __builtin_amdgcn_s_setprio(1);
#pragma unroll
    for (int nt = 0; nt < 4; ++nt) {
      int row = nt * 16 + lr;
      int sw = (row & 7) << 4;
      f16x8 kf0 = *(const f16x8*)((char*)Ks + ((row * 128 + lg * 16) ^ sw));
      f16x8 kf1 = *(const f16x8*)((char*)Ks + ((row * 128 + 64 + lg * 16) ^ sw));
      f32x4 z = {0.f, 0.f, 0.f, 0.f};
      z = __builtin_amdgcn_mfma_f32_16x16x32_f16(kf0, aq0, z, 0, 0, 0);
      s[nt] = __builtin_amdgcn_mfma_f32_16x16x32_f16(kf1, aq1, z, 0, 0, 0);
    }
    __builtin_amdgcn_s_setprio(0);

    // ---- + bias (exp2 domain via fma) ----
#pragma unroll
    for (int nt = 0; nt < 4; ++nt) {
      s[nt][0] = fmaf(bv4[nt].x, LOG2E, s[nt][0]);
      s[nt][1] = fmaf(bv4[nt].y, LOG2E, s[nt][1]);
      s[nt][2] = fmaf(bv4[nt].z, LOG2E, s[nt][2]);
      s[nt][3] = fmaf(bv4[nt].w, LOG2E, s[nt][3]);
    }

    // ---- row max: 15 in-lane + 2 shuffles (q-row is lane-local now) ----
    float pmax = fmaxf(fmaxf(s[0][0], s[0][1]), fmaxf(s[0][2], s[0][3]));
#pragma unroll
    for (int nt = 1; nt < 4; ++nt)
      pmax = fmaxf(pmax, fmaxf(fmaxf(s[nt][0], s[nt][1]), fmaxf(s[nt][2], s[nt][3])));
    pmax = fmaxf(pmax, __shfl_xor(pmax, 16));
    pmax = fmaxf(pmax, __shfl_xor(pmax, 32));

    // ---- defer-max: rescale only when max grew past THR=8 (P <= 2^8, f16-safe) ----
    if (__any(pmax > mrow + 8.0f)) {
      float mn = fmaxf(mrow, pmax);
      float corr = exp2f(mrow - mn);
      mrow = mn;
      lsum *= corr;
#pragma unroll
      for (int nt = 0; nt < 4; ++nt)
#pragma unroll
        for (int r = 0; r < 4; ++r) acc[nt][r] *= corr;
    }

    // ---- P = exp2(S - mrow); row sum: 15 in-lane + 2 shuffles ----
    float rs = 0.f;
#pragma unroll
    for (int nt = 0; nt < 4; ++nt)
#pragma unroll
      for (int r = 0; r < 4; ++r) {
        float p = exp2f(s[nt][r] - mrow);
        s[nt][r] = p;
        rs += p;
      }
    rs += __shfl_xor(rs, 16);
    rs += __shfl_xor(rs, 32);
    lsum += rs;

    // ---- P^T -> per-wave LDS [q][kv] as 4x f16x4 (8B) writes ----
#pragma unroll
    for (int nt = 0; nt < 4; ++nt) {
      f16x4 pk = {(_Float16)s[nt][0], (_Float16)s[nt][1],
                  (_Float16)s[nt][2], (_Float16)s[nt][3]};
      int off = (lr * 128 + nt * 32 + lg * 8) ^ ((lr & 7) << 4);
      *(f16x4*)((char*)Ps[w] + off) = pk;
    }

    // ---- PV swapped: acc^T = mfma(V^T-frag, P^T-frag) ----
    __builtin_amdgcn_s_setprio(1);
#pragma unroll
    for (int kk = 0; kk < 2; ++kk) {
      f16x8 pb = *(const f16x8*)((char*)Ps[w] +
                 ((lr * 128 + kk * 64 + lg * 16) ^ ((lr & 7) << 4)));
#pragma unroll
      for (int nt = 0; nt < 4; ++nt) {
        int row = nt * 16 + lr;
        f16x8 vf = *(const f16x8*)((char*)Vs +
                 ((row * 128 + kk * 64 + lg * 16) ^ ((row & 7) << 4)));
        acc[nt] = __builtin_amdgcn_mfma_f32_16x16x32_f16(vf, pb, acc[nt], 0, 0, 0);
      }
    }
    __builtin_amdgcn_s_setprio(0);
    __syncthreads();
  }

  // ---- normalize + write ctx[b][q=qw+lr][h*64 + nt*16+lg*4+{0..3}] (8B stores) ----
  float inv = 1.0f / lsum;
#pragma unroll
  for (int nt = 0; nt < 4; ++nt) {
    f16x4 o = {(_Float16)(acc[nt][0] * inv), (_Float16)(acc[nt][1] * inv),
               (_Float16)(acc[nt][2] * inv), (_Float16)(acc[nt][3] * inv)};
    *(f16x4*)(ctx + ((size_t)b * NQ_ + qw + lr) * DM_ + h * 64 + nt * 16 + lg * 4) = o;
  }
}

extern "C" void kernel_launch(void* const* d_in, const int* in_sizes, int n_in,
                              void* d_out, int out_size, void* d_ws, size_t ws_size,
                              hipStream_t stream) {
  const float* x    = (const float*)d_in[0];
  const float* enc  = (const float*)d_in[1];
  const float* bias = (const float*)d_in[2];
  const float* Wq   = (const float*)d_in[3];
  const float* Wk   = (const float*)d_in[4];
  const float* Wv   = (const float*)d_in[5];
  const float* Wo   = (const float*)d_in[6];
  char* ws = (char*)d_ws;
  const size_t MiB = 1024 * 1024;
  _Float16* WqT   = (_Float16*)(ws + 0 * MiB);
  _Float16* WkT   = (_Float16*)(ws + 2 * MiB);   // WkT+WvT contiguous: stacked Bt [2048][1024]
  _Float16* WvT   = (_Float16*)(ws + 4 * MiB);
  _Float16* WoT   = (_Float16*)(ws + 6 * MiB);
  _Float16* xf    = (_Float16*)(ws + 8 * MiB);
  _Float16* encf  = (_Float16*)(ws + 24 * MiB);
  _Float16* Qb    = (_Float16*)(ws + 40 * MiB);
  _Float16* KVb   = (_Float16*)(ws + 56 * MiB);  // [8192][2048]: cols 0..1023=K, 1024..2047=V
  _Float16* Vt    = (_Float16*)(ws + 88 * MiB);  // [B][H][64][NKV]
  _Float16* ctxf  = (_Float16*)(ws + 104 * MiB); // [8192][1024]

  wtrans<<<1024, 256, 0, stream>>>(Wq, WqT);
  wtrans<<<1024, 256, 0, stream>>>(Wk, WkT);
  wtrans<<<1024, 256, 0, stream>>>(Wv, WvT);
  wtrans<<<1024, 256, 0, stream>>>(Wo, WoT);
  cast_f16<<<8192, 256, 0, stream>>>(x, xf, 2097152);
  cast_f16<<<8192, 256, 0, stream>>>(enc, encf, 2097152);
  gemm_bt<0><<<512, 256, 0, stream>>>(xf, WqT, Qb, 8192, 1024, 1024);
  gemm_bt<0><<<1024, 256, 0, stream>>>(encf, WkT, KVb, 8192, 2048, 1024);
  vtrans<<<2048, 256, 0, stream>>>(KVb, Vt);
  attn<<<2048, 256, 0, stream>>>(Qb, KVb, Vt, bias, ctxf);
  gemm_bt<1><<<512, 256, 0, stream>>>(ctxf, WoT, d_out, 8192, 1024, 1024);
}